// Round 1
// 225.469 us; speedup vs baseline: 1.0304x; 1.0304x over previous
//
#include <hip/hip_runtime.h>
#include <hip/hip_bf16.h>

typedef __attribute__((ext_vector_type(8))) short bf16x8;
typedef __attribute__((ext_vector_type(4))) float f32x4;

#define B_N   4
#define C_IN  32
#define C_OUT 64
#define S_H   32
#define S_W   64
#define S_D   64
#define HWD   (S_H * S_W * S_D)   /* 131072 */

// ws layout (ushorts): [Wpk 4*28*64*8] only — X is now staged in-kernel.
#define WPK_USHORTS     (4 * 28 * 64 * 8)              /* 57344 */
#define WS_NEEDED       ((size_t)WPK_USHORTS * 2)      /* 114688 B */

__device__ __forceinline__ ushort f2bf(float f) {
    unsigned u = __builtin_bit_cast(unsigned, f);
    unsigned r = (u + 0x7FFFu + ((u >> 16) & 1u)) >> 16;  // RNE
    return (ushort)r;
}

typedef const __attribute__((address_space(1))) unsigned int* dma_gptr;
typedef __attribute__((address_space(3))) unsigned int* dma_lptr;

__device__ __forceinline__ void dma16(const void* g, void* l) {
    __builtin_amdgcn_global_load_lds((dma_gptr)g, (dma_lptr)l, 16, 0, 0);
}

// ---- prep: pack weights [cic][tap28][co64][ci8] bf16 (tap27 = zero pad row)
__global__ __launch_bounds__(256) void pack_w_kernel(
    const float* __restrict__ Wt, ushort* __restrict__ Wpk)
{
    int idx = blockIdx.x * 256 + threadIdx.x;       // 4*28*64 = 7168
    int cic = idx / 1792;
    int r   = idx - cic * 1792;
    int tap = r >> 6;
    int co  = r & 63;
    bf16x8 pk;
    #pragma unroll
    for (int j = 0; j < 8; ++j)
        pk[j] = (tap < 27) ? (short)f2bf(Wt[((long)co * C_IN + cic * 8 + j) * 27 + tap])
                           : (short)0;
    *((bf16x8*)Wpk + idx) = pk;
}

// ---- main: implicit-GEMM conv3d with fused fp32->bf16 X staging ----------
// Block tile 64co x 256n (4w x 64d). Each wave: 64co x 64n (its own w column),
// 4 m-tiles x 4 n-tiles of 16x16x32 MFMA -> 4 A + 4 B ds_read_b128 per k-step
// feeding 16 MFMAs. W staged via global_load_lds (L2-resident Wpk).
// X staged register-side (T14 async split): clamped global loads for cic+1
// issued right after the W barrier, latency hidden under the 112 MFMAs of
// cic, then cvt+ds_write_b128 into the alternate buffer before the barrier.
__global__ __launch_bounds__(256, 2) void conv3d_fused_kernel(
    const float* __restrict__ X, const ushort* __restrict__ Wpk,
    const float* __restrict__ bias, float* __restrict__ out)
{
    __shared__ ushort Xs[2][1188 * 8];   // [hh3][ww6][dpos66][ci8], 19008 B each
    __shared__ ushort Ws[1792 * 8];      // [tap28][co64][ci8]       28672 B

    const int tid  = threadIdx.x;
    const int lane = tid & 63;
    const int wave = tid >> 6;
    const int nl   = lane & 15;
    const int quad = lane >> 4;

    const int blk = blockIdx.x;       // 2048 blocks = (b4, h32, wt16)
    const int wt  = blk & 15;
    const int h   = (blk >> 4) & 31;
    const int b   = blk >> 9;
    const int w0  = wt * 4;

    // ---- per-site X staging pointers (clamped) + in-bounds flags ----------
    const float* xb[5];
    bool oks[5];
    #pragma unroll
    for (int k = 0; k < 5; ++k) {
        int s = tid + k * 256;
        oks[k] = false;
        xb[k]  = X;
        if (s < 1188) {
            int hh   = s / 396;           // 6*66
            int r0   = s - hh * 396;
            int ww   = r0 / 66;
            int dpos = r0 - ww * 66;
            int hp  = h - 1 + hh;
            int wp2 = w0 - 1 + ww;
            int dp  = dpos - 1;
            oks[k] = (unsigned)hp < S_H && (unsigned)wp2 < S_W && (unsigned)dp < S_D;
            int hc = min(max(hp, 0), S_H - 1);
            int wc = min(max(wp2, 0), S_W - 1);
            int dc = min(max(dp, 0), S_D - 1);
            xb[k] = X + ((((long)b * C_IN) * S_H + hc) * S_W + wc) * S_D + dc;
        }
    }

    // ---- per-tg LDS offsets (ushort units) --------------------------------
    int a_off[7], b_off[7];
    #pragma unroll
    for (int tg = 0; tg < 7; ++tg) {
        int tap = tg * 4 + quad;
        int tb  = tap < 27 ? tap : 0;      // pad tap: A rows are zero anyway
        int kh = tb / 9;
        int r9 = tb - kh * 9;
        int kw = r9 / 3;
        int kd = r9 - kw * 3;
        a_off[tg] = (tap * 64 + nl) * 8;
        b_off[tg] = (((kh * 6 + kw + wave) * 66) + kd + nl) * 8;  // ww = wave+kw
    }

    float bs[16];
    #pragma unroll
    for (int mi = 0; mi < 4; ++mi)
        #pragma unroll
        for (int r = 0; r < 4; ++r)
            bs[mi * 4 + r] = bias[mi * 16 + quad * 4 + r];

    f32x4 acc[16];
    #pragma unroll
    for (int i = 0; i < 16; ++i) acc[i] = (f32x4){0.f, 0.f, 0.f, 0.f};

    // ---- prologue: stage X chunk 0 into buf 0 (reg -> cvt -> LDS) ---------
    float xv[5][8];
    #pragma unroll
    for (int k = 0; k < 5; ++k) {
        int s = tid + k * 256;
        if (s < 1188) {
            #pragma unroll
            for (int j = 0; j < 8; ++j) xv[k][j] = xb[k][(long)j * HWD];
        }
    }
    #pragma unroll
    for (int k = 0; k < 5; ++k) {
        int s = tid + k * 256;
        if (s < 1188) {
            bf16x8 pk;
            #pragma unroll
            for (int j = 0; j < 8; ++j)
                pk[j] = oks[k] ? (short)f2bf(xv[k][j]) : (short)0;
            *(bf16x8*)&Xs[0][s * 8] = pk;
        }
    }

    for (int cic = 0; cic < 4; ++cic) {
        __syncthreads();                 // Xs[cic&1] writes visible; Ws free

        // stage W chunk (DMA, L2-resident source)
        {
            const ushort* src = Wpk + (long)cic * 1792 * 8;
            #pragma unroll
            for (int k = 0; k < 7; ++k) {
                int s = tid + k * 256;
                dma16(src + s * 8, &Ws[s * 8]);
            }
        }
        __syncthreads();                 // drains W DMA only (X loads not yet issued)

        // issue X loads for chunk cic+1 -> regs; latency hides under compute
        if (cic < 3) {
            #pragma unroll
            for (int k = 0; k < 5; ++k) {
                int s = tid + k * 256;
                if (s < 1188) {
                    #pragma unroll
                    for (int j = 0; j < 8; ++j)
                        xv[k][j] = xb[k][((long)(cic + 1) * 8 + j) * HWD];
                }
            }
        }

        const ushort* xbuf = Xs[cic & 1];
        #pragma unroll
        for (int tg = 0; tg < 7; ++tg) {
            bf16x8 af[4], bf[4];
            #pragma unroll
            for (int mi = 0; mi < 4; ++mi)
                af[mi] = *(const bf16x8*)&Ws[a_off[tg] + mi * 128];   // +mi*16 co
            #pragma unroll
            for (int dt = 0; dt < 4; ++dt)
                bf[dt] = *(const bf16x8*)&xbuf[b_off[tg] + dt * 128]; // +dt*16 d
            #pragma unroll
            for (int mi = 0; mi < 4; ++mi)
                #pragma unroll
                for (int dt = 0; dt < 4; ++dt)
                    acc[mi * 4 + dt] = __builtin_amdgcn_mfma_f32_16x16x32_bf16(
                        af[mi], bf[dt], acc[mi * 4 + dt], 0, 0, 0);
        }

        // cvt + write chunk cic+1 into the other buffer (waits loads here)
        if (cic < 3) {
            #pragma unroll
            for (int k = 0; k < 5; ++k) {
                int s = tid + k * 256;
                if (s < 1188) {
                    bf16x8 pk;
                    #pragma unroll
                    for (int j = 0; j < 8; ++j)
                        pk[j] = oks[k] ? (short)f2bf(xv[k][j]) : (short)0;
                    *(bf16x8*)&Xs[(cic + 1) & 1][s * 8] = pk;
                }
            }
        }
    }

    // ---- epilogue: co = mi*16 + quad*4 + r, n = (w0+wave, dt*16+nl) -------
    const int w = w0 + wave;
    #pragma unroll
    for (int mi = 0; mi < 4; ++mi) {
        #pragma unroll
        for (int dt = 0; dt < 4; ++dt) {
            f32x4 a = acc[mi * 4 + dt];
            int d0 = dt * 16 + nl;
            #pragma unroll
            for (int r = 0; r < 4; ++r) {
                int co = mi * 16 + quad * 4 + r;
                out[(((long)(b * C_OUT + co) * S_H + h) * S_W + w) * S_D + d0]
                    = a[r] + bs[mi * 4 + r];
            }
        }
    }
}

// ---- fallback (no workspace needed) ---------------------------------------
__global__ __launch_bounds__(256) void conv3d_mfma_fallback(
    const float* __restrict__ X, const float* __restrict__ Wt,
    const float* __restrict__ bias, float* __restrict__ out)
{
    __shared__ ushort Xs[3 * 6 * 66 * 8];
    __shared__ ushort Ws[28 * 64 * 8];

    const int tid  = threadIdx.x;
    const int lane = tid & 63;
    const int wave = tid >> 6;
    const int nl   = lane & 15;
    const int quad = lane >> 4;
    const int co_base = wave * 16;

    const int blk = blockIdx.x;
    const int wt  = blk & 15;
    const int h   = (blk >> 4) & 31;
    const int b   = blk >> 9;
    const int w0  = wt * 4;

    float bs[4];
    #pragma unroll
    for (int r = 0; r < 4; ++r) bs[r] = bias[co_base + quad * 4 + r];

    f32x4 acc[16];
    #pragma unroll
    for (int i = 0; i < 16; ++i) acc[i] = (f32x4){0.f, 0.f, 0.f, 0.f};

    for (int cic = 0; cic < 4; ++cic) {
        __syncthreads();
        for (int s = tid; s < 64 * 27; s += 256) {
            int co = s / 27;
            int t  = s - co * 27;
            const float* wp = Wt + ((long)co * C_IN + cic * 8) * 27 + t;
            bf16x8 pk;
            #pragma unroll
            for (int j = 0; j < 8; ++j) pk[j] = (short)f2bf(wp[j * 27]);
            *(bf16x8*)&Ws[(t * 64 + co) * 8] = pk;
        }
        for (int s = tid; s < 64; s += 256) {
            bf16x8 z;
            #pragma unroll
            for (int j = 0; j < 8; ++j) z[j] = 0;
            *(bf16x8*)&Ws[(27 * 64 + s) * 8] = z;
        }
        for (int s = tid; s < 1188; s += 256) {
            int hh   = s / 396;
            int r0   = s - hh * 396;
            int ww   = r0 / 66;
            int dpos = r0 - ww * 66;
            int hp = h - 1 + hh;
            int wp2 = w0 - 1 + ww;
            int dp = dpos - 1;
            bool ok = (unsigned)hp < S_H && (unsigned)wp2 < S_W && (unsigned)dp < S_D;
            int hc = min(max(hp, 0), S_H - 1);
            int wc = min(max(wp2, 0), S_W - 1);
            int dc = min(max(dp, 0), S_D - 1);
            const float* xp = X + (((long)(b * C_IN + cic * 8) * S_H + hc) * S_W + wc) * S_D + dc;
            bf16x8 pk;
            #pragma unroll
            for (int j = 0; j < 8; ++j) {
                float v = xp[(long)j * HWD];
                pk[j] = ok ? (short)f2bf(v) : (short)0;
            }
            *(bf16x8*)&Xs[s * 8] = pk;
        }
        __syncthreads();

        #pragma unroll
        for (int tg = 0; tg < 7; ++tg) {
            int tap = tg * 4 + quad;
            bf16x8 afrag = *(const bf16x8*)&Ws[(tap * 64 + co_base + nl) * 8];
            int tb = tap < 27 ? tap : 0;
            int kh = tb / 9;
            int r9 = tb - kh * 9;
            int kw = r9 / 3;
            int kd = r9 - kw * 3;
            int bbase = ((kh * 6 + kw) * 66 + kd + nl) * 8;
            #pragma unroll
            for (int wi = 0; wi < 4; ++wi) {
                #pragma unroll
                for (int dt = 0; dt < 4; ++dt) {
                    bf16x8 bfrag = *(const bf16x8*)&Xs[bbase + wi * (66 * 8) + dt * (16 * 8)];
                    acc[wi * 4 + dt] = __builtin_amdgcn_mfma_f32_16x16x32_bf16(
                        afrag, bfrag, acc[wi * 4 + dt], 0, 0, 0);
                }
            }
        }
    }

    #pragma unroll
    for (int wi = 0; wi < 4; ++wi) {
        int w = w0 + wi;
        #pragma unroll
        for (int dt = 0; dt < 4; ++dt) {
            int d0 = dt * 16 + nl;
            f32x4 a = acc[wi * 4 + dt];
            #pragma unroll
            for (int r = 0; r < 4; ++r) {
                int co = co_base + quad * 4 + r;
                out[(((long)(b * C_OUT + co) * S_H + h) * S_W + w) * S_D + d0] = a[r] + bs[r];
            }
        }
    }
}

extern "C" void kernel_launch(void* const* d_in, const int* in_sizes, int n_in,
                              void* d_out, int out_size, void* d_ws, size_t ws_size,
                              hipStream_t stream) {
    const float* X    = (const float*)d_in[0];
    const float* Wt   = (const float*)d_in[1];
    const float* bias = (const float*)d_in[2];
    float* out = (float*)d_out;

    if (ws_size >= WS_NEEDED) {
        ushort* Wpk = (ushort*)d_ws;
        pack_w_kernel<<<dim3(28),   dim3(256), 0, stream>>>(Wt, Wpk);
        conv3d_fused_kernel<<<dim3(2048), dim3(256), 0, stream>>>(X, Wpk, bias, out);
    } else {
        conv3d_mfma_fallback<<<dim3(2048), dim3(256), 0, stream>>>(X, Wt, bias, out);
    }
}